// Round 1
// baseline (1104.598 us; speedup 1.0000x reference)
//
#include <hip/hip_runtime.h>
#include <math.h>

#define NI 1024        // NUM_INPUTS
#define NH 1024        // NUM_HIDDEN
#define H4 4096        // 4*NUM_HIDDEN
#define FORGET_GATE_BIAS (-1.0f)
#define LN_EPS 1e-5f

// ---------------------------------------------------------------------------
// C[M,N] = A[M,K] @ W[N,K]^T + bias[N]
// 64x64 tile, 256 threads, 4x4 micro-tile per thread, K-tile = 16.
// ---------------------------------------------------------------------------
__global__ __launch_bounds__(256) void gemm_nt_bias(
    const float* __restrict__ A,    // [M,K] row-major
    const float* __restrict__ W,    // [N,K] row-major
    const float* __restrict__ bias, // [N]
    float* __restrict__ C,          // [M,N] row-major
    int M, int N, int K)
{
    __shared__ float As[16][64];    // [k][m]
    __shared__ float Ws[16][64];    // [k][n]

    const int tx = threadIdx.x & 15;   // n-dim thread coord
    const int ty = threadIdx.x >> 4;   // m-dim thread coord
    const int m0 = blockIdx.y * 64;
    const int n0 = blockIdx.x * 64;

    float acc[4][4] = {};

    // staging coords: each thread loads one float4 of A and one of W per k-tile
    const int lrow = threadIdx.x >> 2;        // 0..63 tile row
    const int lk4  = (threadIdx.x & 3) * 4;   // 0,4,8,12 k offset
    const float* Aptr = A + (size_t)(m0 + lrow) * K + lk4;
    const float* Wptr = W + (size_t)(n0 + lrow) * K + lk4;

    for (int k0 = 0; k0 < K; k0 += 16) {
        float4 av = *(const float4*)(Aptr + k0);
        float4 wv = *(const float4*)(Wptr + k0);
        __syncthreads();   // previous iteration's LDS reads complete
        As[lk4 + 0][lrow] = av.x;
        As[lk4 + 1][lrow] = av.y;
        As[lk4 + 2][lrow] = av.z;
        As[lk4 + 3][lrow] = av.w;
        Ws[lk4 + 0][lrow] = wv.x;
        Ws[lk4 + 1][lrow] = wv.y;
        Ws[lk4 + 2][lrow] = wv.z;
        Ws[lk4 + 3][lrow] = wv.w;
        __syncthreads();

#pragma unroll
        for (int kk = 0; kk < 16; ++kk) {
            float a[4], b[4];
#pragma unroll
            for (int i = 0; i < 4; ++i) a[i] = As[kk][ty * 4 + i];
#pragma unroll
            for (int j = 0; j < 4; ++j) b[j] = Ws[kk][tx * 4 + j];
#pragma unroll
            for (int i = 0; i < 4; ++i)
#pragma unroll
                for (int j = 0; j < 4; ++j)
                    acc[i][j] += a[i] * b[j];
        }
    }

    // epilogue: contiguous float4 store per row of the micro-tile
#pragma unroll
    for (int i = 0; i < 4; ++i) {
        const int m = m0 + ty * 4 + i;
        const int n = n0 + tx * 4;
        float4 bv = *(const float4*)(bias + n);
        float4 cv;
        cv.x = acc[i][0] + bv.x;
        cv.y = acc[i][1] + bv.y;
        cv.z = acc[i][2] + bv.z;
        cv.w = acc[i][3] + bv.w;
        *(float4*)(C + (size_t)m * N + n) = cv;
    }
}

// ---------------------------------------------------------------------------
// Per-row: LN(i2h) + LN(h2h) -> gates -> cx_new -> LN -> hx_new
// One block (256 threads) per batch row.
// ---------------------------------------------------------------------------
__device__ __forceinline__ float sigmoidf(float x) {
    return 1.0f / (1.0f + expf(-x));
}

__global__ __launch_bounds__(256) void lstm_pointwise(
    const float* __restrict__ i2h,      // [B, 4H]
    const float* __restrict__ h2h,      // [B, 4H]
    const float* __restrict__ cx,       // [B, H]
    const float* __restrict__ lwx, const float* __restrict__ lbx,  // ln_i2h
    const float* __restrict__ lwy, const float* __restrict__ lby,  // ln_h2h
    const float* __restrict__ lwc, const float* __restrict__ lbc,  // ln_h2o
    float* __restrict__ hx_out,         // [B, H]
    float* __restrict__ cx_out)         // [B, H]
{
    __shared__ float sX[H4];
    __shared__ float sY[H4];
    __shared__ float sC[NH];
    __shared__ float red[16];

    const int row  = blockIdx.x;
    const int tid  = threadIdx.x;
    const int lane = tid & 63;
    const int wid  = tid >> 6;

    const float* xrow = i2h + (size_t)row * H4;
    const float* yrow = h2h + (size_t)row * H4;

    // phase 1: stage rows into LDS, accumulate sum / sumsq
    float sx = 0.f, sxx = 0.f, sy = 0.f, syy = 0.f;
    for (int p = tid; p < H4; p += 256) {
        float x = xrow[p]; sX[p] = x; sx += x; sxx += x * x;
        float y = yrow[p]; sY[p] = y; sy += y; syy += y * y;
    }
#pragma unroll
    for (int off = 32; off; off >>= 1) {
        sx  += __shfl_down(sx,  off, 64);
        sxx += __shfl_down(sxx, off, 64);
        sy  += __shfl_down(sy,  off, 64);
        syy += __shfl_down(syy, off, 64);
    }
    if (lane == 0) {
        red[wid] = sx; red[4 + wid] = sxx; red[8 + wid] = sy; red[12 + wid] = syy;
    }
    __syncthreads();
    const float tsx  = red[0] + red[1] + red[2] + red[3];
    const float tsxx = red[4] + red[5] + red[6] + red[7];
    const float tsy  = red[8] + red[9] + red[10] + red[11];
    const float tsyy = red[12] + red[13] + red[14] + red[15];
    __syncthreads();   // red will be reused

    const float n1  = (float)H4;
    const float mx  = tsx / n1;
    const float vx  = fmaxf((tsxx - tsx * tsx / n1) / (n1 - 1.0f), 0.0f);
    const float ivx = 1.0f / (sqrtf(vx) + LN_EPS);
    const float my  = tsy / n1;
    const float vy  = fmaxf((tsyy - tsy * tsy / n1) / (n1 - 1.0f), 0.0f);
    const float ivy = 1.0f / (sqrtf(vy) + LN_EPS);

    // phase 2: gates + cx_new (each thread owns 4 j positions)
    float og[4];
    float sc = 0.f, scc = 0.f;
    {
        int k = 0;
        for (int j = tid; j < NH; j += 256, ++k) {
            const int p0 = j, p1 = j + NH, p2 = j + 2 * NH, p3 = j + 3 * NH;
            float g_i = (sX[p0] - mx) * ivx * lwx[p0] + lbx[p0]
                      + (sY[p0] - my) * ivy * lwy[p0] + lby[p0];
            float g_f = (sX[p1] - mx) * ivx * lwx[p1] + lbx[p1]
                      + (sY[p1] - my) * ivy * lwy[p1] + lby[p1];
            float g_o = (sX[p2] - mx) * ivx * lwx[p2] + lbx[p2]
                      + (sY[p2] - my) * ivy * lwy[p2] + lby[p2];
            float g_c = (sX[p3] - mx) * ivx * lwx[p3] + lbx[p3]
                      + (sY[p3] - my) * ivy * lwy[p3] + lby[p3];

            float in_g   = sigmoidf(g_i);
            float fg     = sigmoidf(g_f + FORGET_GATE_BIAS);
            float out_g  = sigmoidf(g_o);
            float in_tr  = tanhf(g_c);

            float c = fg * cx[(size_t)row * NH + j] + in_g * in_tr;
            sC[j] = c;
            cx_out[(size_t)row * NH + j] = c;
            og[k] = out_g;
            sc += c; scc += c * c;
        }
    }

#pragma unroll
    for (int off = 32; off; off >>= 1) {
        sc  += __shfl_down(sc,  off, 64);
        scc += __shfl_down(scc, off, 64);
    }
    if (lane == 0) { red[wid] = sc; red[4 + wid] = scc; }
    __syncthreads();
    const float tsc  = red[0] + red[1] + red[2] + red[3];
    const float tscc = red[4] + red[5] + red[6] + red[7];

    const float nc  = (float)NH;
    const float mc  = tsc / nc;
    const float vc  = fmaxf((tscc - tsc * tsc / nc) / (nc - 1.0f), 0.0f);
    const float ivc = 1.0f / (sqrtf(vc) + LN_EPS);

    // phase 3: hx_new
    {
        int k = 0;
        for (int j = tid; j < NH; j += 256, ++k) {
            float t = tanhf((sC[j] - mc) * ivc * lwc[j] + lbc[j]);
            hx_out[(size_t)row * NH + j] = og[k] * t;
        }
    }
}

// ---------------------------------------------------------------------------
extern "C" void kernel_launch(void* const* d_in, const int* in_sizes, int n_in,
                              void* d_out, int out_size, void* d_ws, size_t ws_size,
                              hipStream_t stream) {
    const float* inputs = (const float*)d_in[0];   // [B, NI]
    const float* hx     = (const float*)d_in[1];   // [B, NH]
    const float* cx     = (const float*)d_in[2];   // [B, NH]
    const float* w_i2h  = (const float*)d_in[3];   // [4H, NI]
    const float* b_i2h  = (const float*)d_in[4];   // [4H]
    const float* w_h2h  = (const float*)d_in[5];   // [4H, NH]
    const float* b_h2h  = (const float*)d_in[6];   // [4H]
    const float* lwx    = (const float*)d_in[7];
    const float* lbx    = (const float*)d_in[8];
    const float* lwy    = (const float*)d_in[9];
    const float* lby    = (const float*)d_in[10];
    const float* lwc    = (const float*)d_in[11];
    const float* lbc    = (const float*)d_in[12];

    const int B = in_sizes[0] / NI;                // 4096

    float* i2h = (float*)d_ws;                     // [B, 4H]
    float* h2h = i2h + (size_t)B * H4;             // [B, 4H]

    float* hx_out = (float*)d_out;                 // [B, NH]
    float* cx_out = hx_out + (size_t)B * NH;       // [B, NH]

    dim3 gblk(256);
    dim3 ggrid(H4 / 64, B / 64);
    gemm_nt_bias<<<ggrid, gblk, 0, stream>>>(inputs, w_i2h, b_i2h, i2h, B, H4, NI);
    gemm_nt_bias<<<ggrid, gblk, 0, stream>>>(hx,     w_h2h, b_h2h, h2h, B, H4, NH);

    lstm_pointwise<<<dim3(B), dim3(256), 0, stream>>>(
        i2h, h2h, cx, lwx, lbx, lwy, lby, lwc, lbc, hx_out, cx_out);
}

// Round 2
// 262.817 us; speedup vs baseline: 4.2029x; 4.2029x over previous
//
#include <hip/hip_runtime.h>
#include <hip/hip_bf16.h>
#include <math.h>

#define NI 1024        // NUM_INPUTS
#define NH 1024        // NUM_HIDDEN
#define H4 4096        // 4*NUM_HIDDEN
#define FGB (-1.0f)
#define LN_EPS 1e-5f

typedef unsigned short u16;
typedef __attribute__((ext_vector_type(8))) short short8;   // 8 bf16 = 4 VGPRs
typedef __attribute__((ext_vector_type(4))) float f32x4;

__device__ __forceinline__ float bf2f(u16 u) {
    union { unsigned int i; float f; } v; v.i = ((unsigned int)u) << 16; return v.f;
}
__device__ __forceinline__ u16 f2bf(float f) {
    __hip_bfloat16 h = __float2bfloat16(f);   // RNE
    return __builtin_bit_cast(u16, h);
}
__device__ __forceinline__ float fast_sigmoid(float x) {
    return 1.0f / (1.0f + __expf(-x));
}
__device__ __forceinline__ float fast_tanh(float x) {
    return 1.0f - 2.0f / (__expf(2.0f * x) + 1.0f);
}
// async global->LDS, 16 B per lane; lds dest = wave-uniform base + lane*16
__device__ __forceinline__ void gload_lds16(const u16* g, u16* l) {
    __builtin_amdgcn_global_load_lds(
        (__attribute__((address_space(1))) void*)(g),
        (__attribute__((address_space(3))) void*)(l), 16, 0, 0);
}

// ---------------------------------------------------------------------------
// fp32 -> bf16 cast for the four GEMM operands (all 4M elements each)
// ---------------------------------------------------------------------------
__global__ __launch_bounds__(256) void cast4(
    const float* __restrict__ a, const float* __restrict__ b,
    const float* __restrict__ c, const float* __restrict__ d,
    u16* __restrict__ oa, u16* __restrict__ ob,
    u16* __restrict__ oc, u16* __restrict__ od)
{
    const int i = (blockIdx.x * 256 + threadIdx.x) * 4;
    float4 av = *(const float4*)(a + i);
    float4 bv = *(const float4*)(b + i);
    float4 cv = *(const float4*)(c + i);
    float4 dv = *(const float4*)(d + i);
    *(ushort4*)(oa + i) = make_ushort4(f2bf(av.x), f2bf(av.y), f2bf(av.z), f2bf(av.w));
    *(ushort4*)(ob + i) = make_ushort4(f2bf(bv.x), f2bf(bv.y), f2bf(bv.z), f2bf(bv.w));
    *(ushort4*)(oc + i) = make_ushort4(f2bf(cv.x), f2bf(cv.y), f2bf(cv.z), f2bf(cv.w));
    *(ushort4*)(od + i) = make_ushort4(f2bf(dv.x), f2bf(dv.y), f2bf(dv.z), f2bf(dv.w));
}

// ---------------------------------------------------------------------------
// C[M,N](bf16) = A[M,K](bf16) @ W[N,K](bf16)^T + bias[N](fp32)
// m97 structure: 128x128 tile, BK=32, 4 waves, 4x4 16x16x32 MFMA per wave,
// global_load_lds width=16 staging. blockIdx.z picks GEMM 0/1.
// ---------------------------------------------------------------------------
__global__ __launch_bounds__(256) void gemm_bt_bf16(
    const u16* __restrict__ A0, const u16* __restrict__ W0,
    const float* __restrict__ bias0, u16* __restrict__ C0,
    const u16* __restrict__ A1, const u16* __restrict__ W1,
    const float* __restrict__ bias1, u16* __restrict__ C1,
    int M, int N, int K)
{
    const u16*  A    = blockIdx.z ? A1 : A0;
    const u16*  W    = blockIdx.z ? W1 : W0;
    const float* bias = blockIdx.z ? bias1 : bias0;
    u16*        C    = blockIdx.z ? C1 : C0;

    __shared__ u16 sA[128 * 32];   // [m][k] row-major, 8 KB
    __shared__ u16 sB[128 * 32];   // [n][k] row-major, 8 KB

    const int tid  = threadIdx.x;
    const int lane = tid & 63;
    const int wave = tid >> 6;
    const int wm   = wave & 1;
    const int wn   = wave >> 1;
    const int m0   = blockIdx.y * 128;
    const int n0   = blockIdx.x * 128;

    f32x4 acc[4][4];
#pragma unroll
    for (int i = 0; i < 4; ++i)
#pragma unroll
        for (int j = 0; j < 4; ++j)
            acc[i][j] = (f32x4){0.f, 0.f, 0.f, 0.f};

    // staging: 512 chunks of 16B per tile; chunk c -> row c>>2, kcol (c&3)*8
    const int c0 = wave * 64 + lane;
    const int c1 = c0 + 256;
    const int r0 = c0 >> 2, kc0 = (c0 & 3) * 8;
    const int r1 = c1 >> 2, kc1 = (c1 & 3) * 8;
    const u16* gA0 = A + (size_t)(m0 + r0) * K + kc0;
    const u16* gA1 = A + (size_t)(m0 + r1) * K + kc1;
    const u16* gW0 = W + (size_t)(n0 + r0) * K + kc0;
    const u16* gW1 = W + (size_t)(n0 + r1) * K + kc1;
    u16* lA0 = sA + (size_t)(wave * 64) * 8;         // wave-uniform LDS bases
    u16* lA1 = sA + (size_t)(256 + wave * 64) * 8;
    u16* lB0 = sB + (size_t)(wave * 64) * 8;
    u16* lB1 = sB + (size_t)(256 + wave * 64) * 8;

    // fragment read offsets (A: m=lane&15, k=(lane>>4)*8; B symmetric)
    const int aoff = (wm * 64 + (lane & 15)) * 32 + (lane >> 4) * 8;
    const int boff = (wn * 64 + (lane & 15)) * 32 + (lane >> 4) * 8;

    for (int k0 = 0; k0 < K; k0 += 32) {
        __syncthreads();                 // LDS safe to overwrite
        gload_lds16(gA0 + k0, lA0);
        gload_lds16(gA1 + k0, lA1);
        gload_lds16(gW0 + k0, lB0);
        gload_lds16(gW1 + k0, lB1);
        __syncthreads();                 // staging complete (vmcnt drained)

        short8 af[4], bfr[4];
#pragma unroll
        for (int t = 0; t < 4; ++t) {
            af[t]  = *(const short8*)(sA + aoff + t * 16 * 32);
            bfr[t] = *(const short8*)(sB + boff + t * 16 * 32);
        }
#pragma unroll
        for (int tm = 0; tm < 4; ++tm)
#pragma unroll
            for (int tn = 0; tn < 4; ++tn)
                acc[tm][tn] = __builtin_amdgcn_mfma_f32_16x16x32_bf16(
                    af[tm], bfr[tn], acc[tm][tn], 0, 0, 0);
    }

    // epilogue: C/D layout col=lane&15, row=(lane>>4)*4+reg
    float bv[4];
#pragma unroll
    for (int tn = 0; tn < 4; ++tn)
        bv[tn] = bias[n0 + wn * 64 + tn * 16 + (lane & 15)];

    const int orow0 = m0 + wm * 64 + (lane >> 4) * 4;
    const int ocol0 = n0 + wn * 64 + (lane & 15);
#pragma unroll
    for (int tm = 0; tm < 4; ++tm)
#pragma unroll
        for (int tn = 0; tn < 4; ++tn)
#pragma unroll
            for (int r = 0; r < 4; ++r) {
                const int row = orow0 + tm * 16 + r;
                const int col = ocol0 + tn * 16;
                C[(size_t)row * N + col] = f2bf(acc[tm][tn][r] + bv[tn]);
            }
}

// ---------------------------------------------------------------------------
// Pointwise: LN(i2h)+LN(h2h) -> gates -> cx_new -> LN -> hx_new
// One block per batch row; thread t owns j = t*4..t*4+3 across all 4 gates.
// No big LDS staging — gate-aligned ushort4 loads.
// ---------------------------------------------------------------------------
__global__ __launch_bounds__(256) void lstm_pointwise(
    const u16* __restrict__ i2h, const u16* __restrict__ h2h,
    const float* __restrict__ cx,
    const float* __restrict__ lwx, const float* __restrict__ lbx,
    const float* __restrict__ lwy, const float* __restrict__ lby,
    const float* __restrict__ lwc, const float* __restrict__ lbc,
    float* __restrict__ hx_out, float* __restrict__ cx_out)
{
    __shared__ float red[16];
    const int row  = blockIdx.x;
    const int tid  = threadIdx.x;
    const int lane = tid & 63;
    const int wid  = tid >> 6;
    const int j0   = tid * 4;

    const u16* xr = i2h + (size_t)row * H4;
    const u16* yr = h2h + (size_t)row * H4;

    float xg[4][4], yg[4][4];
    float sx = 0.f, sxx = 0.f, sy = 0.f, syy = 0.f;
#pragma unroll
    for (int g = 0; g < 4; ++g) {
        ushort4 xv = *(const ushort4*)(xr + g * NH + j0);
        ushort4 yv = *(const ushort4*)(yr + g * NH + j0);
        float x0 = bf2f(xv.x), x1 = bf2f(xv.y), x2 = bf2f(xv.z), x3 = bf2f(xv.w);
        float y0 = bf2f(yv.x), y1 = bf2f(yv.y), y2 = bf2f(yv.z), y3 = bf2f(yv.w);
        xg[g][0] = x0; xg[g][1] = x1; xg[g][2] = x2; xg[g][3] = x3;
        yg[g][0] = y0; yg[g][1] = y1; yg[g][2] = y2; yg[g][3] = y3;
        sx  += x0 + x1 + x2 + x3;
        sxx += x0 * x0 + x1 * x1 + x2 * x2 + x3 * x3;
        sy  += y0 + y1 + y2 + y3;
        syy += y0 * y0 + y1 * y1 + y2 * y2 + y3 * y3;
    }
#pragma unroll
    for (int off = 32; off; off >>= 1) {
        sx  += __shfl_down(sx,  off, 64);
        sxx += __shfl_down(sxx, off, 64);
        sy  += __shfl_down(sy,  off, 64);
        syy += __shfl_down(syy, off, 64);
    }
    if (lane == 0) {
        red[wid] = sx; red[4 + wid] = sxx; red[8 + wid] = sy; red[12 + wid] = syy;
    }
    __syncthreads();
    const float tsx  = red[0] + red[1] + red[2] + red[3];
    const float tsxx = red[4] + red[5] + red[6] + red[7];
    const float tsy  = red[8] + red[9] + red[10] + red[11];
    const float tsyy = red[12] + red[13] + red[14] + red[15];
    __syncthreads();   // red reused below

    const float n1  = (float)H4;
    const float mx  = tsx / n1;
    const float vx  = fmaxf((tsxx - tsx * tsx / n1) / (n1 - 1.0f), 0.0f);
    const float ivx = 1.0f / (sqrtf(vx) + LN_EPS);
    const float my  = tsy / n1;
    const float vy  = fmaxf((tsyy - tsy * tsy / n1) / (n1 - 1.0f), 0.0f);
    const float ivy = 1.0f / (sqrtf(vy) + LN_EPS);

    // gates
    float gate[4][4];
#pragma unroll
    for (int g = 0; g < 4; ++g) {
        float4 wxv = *(const float4*)(lwx + g * NH + j0);
        float4 bxv = *(const float4*)(lbx + g * NH + j0);
        float4 wyv = *(const float4*)(lwy + g * NH + j0);
        float4 byv = *(const float4*)(lby + g * NH + j0);
        gate[g][0] = (xg[g][0] - mx) * ivx * wxv.x + bxv.x + (yg[g][0] - my) * ivy * wyv.x + byv.x;
        gate[g][1] = (xg[g][1] - mx) * ivx * wxv.y + bxv.y + (yg[g][1] - my) * ivy * wyv.y + byv.y;
        gate[g][2] = (xg[g][2] - mx) * ivx * wxv.z + bxv.z + (yg[g][2] - my) * ivy * wyv.z + byv.z;
        gate[g][3] = (xg[g][3] - mx) * ivx * wxv.w + bxv.w + (yg[g][3] - my) * ivy * wyv.w + byv.w;
    }

    float4 cxv = *(const float4*)(cx + (size_t)row * NH + j0);
    float cvl[4], og[4];
    float sc = 0.f, scc = 0.f;
    {
        const float cin[4] = {cxv.x, cxv.y, cxv.z, cxv.w};
#pragma unroll
        for (int e = 0; e < 4; ++e) {
            float in_g  = fast_sigmoid(gate[0][e]);
            float fg    = fast_sigmoid(gate[1][e] + FGB);
            og[e]       = fast_sigmoid(gate[2][e]);
            float tr    = fast_tanh(gate[3][e]);
            float c     = fg * cin[e] + in_g * tr;
            cvl[e] = c; sc += c; scc += c * c;
        }
    }
    *(float4*)(cx_out + (size_t)row * NH + j0) = make_float4(cvl[0], cvl[1], cvl[2], cvl[3]);

#pragma unroll
    for (int off = 32; off; off >>= 1) {
        sc  += __shfl_down(sc,  off, 64);
        scc += __shfl_down(scc, off, 64);
    }
    if (lane == 0) { red[wid] = sc; red[4 + wid] = scc; }
    __syncthreads();
    const float tsc  = red[0] + red[1] + red[2] + red[3];
    const float tscc = red[4] + red[5] + red[6] + red[7];

    const float nc  = (float)NH;
    const float mc  = tsc / nc;
    const float vc  = fmaxf((tscc - tsc * tsc / nc) / (nc - 1.0f), 0.0f);
    const float ivc = 1.0f / (sqrtf(vc) + LN_EPS);

    float4 wcv = *(const float4*)(lwc + j0);
    float4 bcv = *(const float4*)(lbc + j0);
    float h0 = og[0] * fast_tanh((cvl[0] - mc) * ivc * wcv.x + bcv.x);
    float h1 = og[1] * fast_tanh((cvl[1] - mc) * ivc * wcv.y + bcv.y);
    float h2 = og[2] * fast_tanh((cvl[2] - mc) * ivc * wcv.z + bcv.z);
    float h3 = og[3] * fast_tanh((cvl[3] - mc) * ivc * wcv.w + bcv.w);
    *(float4*)(hx_out + (size_t)row * NH + j0) = make_float4(h0, h1, h2, h3);
}

// ---------------------------------------------------------------------------
extern "C" void kernel_launch(void* const* d_in, const int* in_sizes, int n_in,
                              void* d_out, int out_size, void* d_ws, size_t ws_size,
                              hipStream_t stream) {
    const float* inputs = (const float*)d_in[0];   // [B, NI]
    const float* hx     = (const float*)d_in[1];   // [B, NH]
    const float* cx     = (const float*)d_in[2];   // [B, NH]
    const float* w_i2h  = (const float*)d_in[3];   // [4H, NI]
    const float* b_i2h  = (const float*)d_in[4];   // [4H]
    const float* w_h2h  = (const float*)d_in[5];   // [4H, NH]
    const float* b_h2h  = (const float*)d_in[6];   // [4H]
    const float* lwx    = (const float*)d_in[7];
    const float* lbx    = (const float*)d_in[8];
    const float* lwy    = (const float*)d_in[9];
    const float* lby    = (const float*)d_in[10];
    const float* lwc    = (const float*)d_in[11];
    const float* lbc    = (const float*)d_in[12];

    const int B = in_sizes[0] / NI;                // 4096

    // ws layout (bf16): 4 casts @4M + 2 gemm outs @16M = 96 MB
    u16* a_bf   = (u16*)d_ws;
    u16* hx_bf  = a_bf   + (size_t)B * NI;
    u16* wi_bf  = hx_bf  + (size_t)B * NH;
    u16* wh_bf  = wi_bf  + (size_t)H4 * NI;
    u16* i2h_bf = wh_bf  + (size_t)H4 * NH;
    u16* h2h_bf = i2h_bf + (size_t)B * H4;

    float* hx_out = (float*)d_out;
    float* cx_out = hx_out + (size_t)B * NH;

    cast4<<<dim3((B * NI) / (256 * 4)), dim3(256), 0, stream>>>(
        inputs, hx, w_i2h, w_h2h, a_bf, hx_bf, wi_bf, wh_bf);

    gemm_bt_bf16<<<dim3(H4 / 128, B / 128, 2), dim3(256), 0, stream>>>(
        a_bf, wi_bf, b_i2h, i2h_bf,
        hx_bf, wh_bf, b_h2h, h2h_bf,
        B, H4, NI);

    lstm_pointwise<<<dim3(B), dim3(256), 0, stream>>>(
        i2h_bf, h2h_bf, cx, lwx, lbx, lwy, lby, lwc, lbc, hx_out, cx_out);
}